// Round 5
// baseline (356.958 us; speedup 1.0000x reference)
//
#include <hip/hip_runtime.h>
#include <hip/hip_bf16.h>
#include <stdint.h>

#define BATCH 8
#define SEQ   2048
#define DIM   1024

typedef unsigned short u16;
typedef __attribute__((ext_vector_type(8))) short short8;
typedef __attribute__((ext_vector_type(4))) float f32x4;
typedef __attribute__((ext_vector_type(4))) unsigned short us4;

__device__ __forceinline__ u16 f2bf(float x){
  union { float f; uint32_t u; } c; c.f = x;
  uint32_t u = c.u;
  uint32_t r = u + 0x7fffu + ((u >> 16) & 1u);
  return (u16)(r >> 16);
}
__device__ __forceinline__ float bf2f(u16 s){
  union { uint32_t u; float f; } c; c.u = ((uint32_t)s) << 16;
  return c.f;
}

// async global->LDS, 16B per lane. LDS dest is wave-uniform base + lane*16.
__device__ __forceinline__ void gload16(const void* g, void* l){
  __builtin_amdgcn_global_load_lds(
      (const __attribute__((address_space(1))) void*)g,
      (__attribute__((address_space(3))) void*)l, 16, 0, 0);
}

// ---------- split fp32 [R][1024] -> u16 [R][2048] rows packed [hi|lo] ----------
__global__ __launch_bounds__(256) void k_split(const float* __restrict__ src,
                                               u16* __restrict__ dst, int nchunk){
  for (int i = blockIdx.x*blockDim.x + threadIdx.x; i < nchunk; i += gridDim.x*blockDim.x){
    int r = i >> 8;
    int c = (i & 255) << 2;
    f32x4 v = *(const f32x4*)(src + (size_t)r*DIM + c);
    us4 h, l;
    #pragma unroll
    for (int j = 0; j < 4; j++){
      u16 hh = f2bf(v[j]);
      h[j] = hh;
      l[j] = f2bf(v[j] - bf2f(hh));
    }
    u16* d = dst + (size_t)r*(2*DIM) + c;
    *(us4*)d         = h;
    *(us4*)(d + DIM) = l;
  }
}

// ---------- transpose + split: X[s][d] -> Xt[d][s](hi), Xt[d][2048+s](lo) ----------
// 64x64 tiles, vectorized 16B loads and 8B stores.
__global__ __launch_bounds__(256) void k_convert_vt(const float* __restrict__ V,
                                                    u16* __restrict__ Vts){
  __shared__ float tile[64][65];
  int z = blockIdx.z;
  const float* Vb = V + (size_t)z * SEQ * DIM;
  u16* Vtb = Vts + (size_t)z * DIM * (2*SEQ);
  int s0 = blockIdx.x * 64, d0 = blockIdx.y * 64;
  int t = threadIdx.x;
  int rs = t >> 4;            // 0..15 (s row group)
  int cd = (t & 15) * 4;      // d within tile
  #pragma unroll
  for (int i = 0; i < 4; i++){
    int s = rs + i*16;
    f32x4 v = *(const f32x4*)(Vb + (size_t)(s0 + s)*DIM + d0 + cd);
    tile[s][cd+0] = v[0]; tile[s][cd+1] = v[1];
    tile[s][cd+2] = v[2]; tile[s][cd+3] = v[3];
  }
  __syncthreads();
  int dl = t >> 4;            // d row group
  int sl = (t & 15) * 4;      // s within tile
  #pragma unroll
  for (int i = 0; i < 4; i++){
    int d = dl + i*16;
    us4 h, l;
    #pragma unroll
    for (int j = 0; j < 4; j++){
      float x = tile[sl+j][d];
      u16 hh = f2bf(x);
      h[j] = hh;
      l[j] = f2bf(x - bf2f(hh));
    }
    size_t off = (size_t)(d0 + d) * (2*SEQ) + s0 + sl;
    *(us4*)(Vtb + off)       = h;
    *(us4*)(Vtb + off + SEQ) = l;
  }
}

// ---------- GEMM C = A * B^T, hi/lo split, BK=64, dbuf prefetch-1, swizzled ----------
// A: [M][2*KB] u16 rows packed [hi|lo]; B: [N_][2*KB] u16 packed [hi|lo].
// 1-D grid, XCD-aware rectangles. SPLITOUT=1: C=acc/32 split u16 [M][2*N_];
// SPLITOUT=0: C=acc fp32 [M][N_].
template<int N_, int KB, int SPLITOUT, int BX, int RX, int RY>
__global__ __launch_bounds__(256,1) void k_gemm(const u16* __restrict__ A,
                                                const u16* __restrict__ B,
                                                void* __restrict__ Cout,
                                                size_t aStride, size_t bStride, size_t cStride){
  constexpr int LA = 2*KB;
  // [buf][array: Ah,Al,Bh,Bl][128 rows x 64 elems]
  __shared__ __align__(16) u16 lds[2][4][128*64];

  int orig = blockIdx.x;
  int xcd = orig & 7;
  int idx = orig >> 3;
  constexpr int RN = RX * RY;
  int z  = idx / RN;
  int r  = idx % RN;
  int bx = (xcd % (BX/RX)) * RX + (r % RX);
  int by = (xcd / (BX/RX)) * RY + (r / RX);

  const u16* Ab = A + (size_t)z * aStride;
  const u16* Bb = B + (size_t)z * bStride;

  int t = threadIdx.x, lane = t & 63, w = t >> 6;
  int wm = (w & 1) * 64, wn = (w >> 1) * 64;
  int fr = lane & 15;

  // staging: chunk c covers rows [c*8, c*8+8); lane -> row c*8+(lane>>3),
  // fetches global 8-elem slot ((lane&7) ^ (lane>>3)) -> LDS slot (lane&7) (linear).
  int srow    = lane >> 3;
  int srcSlot = ((lane & 7) ^ (lane >> 3)) * 8;

  const u16* aBase = Ab + ((size_t)bx*128) * LA + srcSlot;
  const u16* bBase = Bb + ((size_t)by*128) * LA + srcSlot;

  // read slots (XOR matches staging): global slot ksub*4+(lane>>4), xor row&7
  int rdSlot0 = (((0*4) + (lane >> 4)) ^ (lane & 7)) * 8;
  int rdSlot1 = (((1*4) + (lane >> 4)) ^ (lane & 7)) * 8;

  f32x4 acc[4][4] = {};

  #define STAGE(buf, k0)                                                      \
    { _Pragma("unroll")                                                       \
      for (int j = 0; j < 4; j++){                                            \
        int c = w*4 + j;                                                      \
        size_t rOff = (size_t)(c*8 + srow) * LA + (k0);                       \
        const u16* ga = aBase + rOff;                                         \
        const u16* gb = bBase + rOff;                                         \
        int le = c * 512;                                                     \
        gload16(ga,      &lds[buf][0][le]);                                   \
        gload16(ga + KB, &lds[buf][1][le]);                                   \
        gload16(gb,      &lds[buf][2][le]);                                   \
        gload16(gb + KB, &lds[buf][3][le]);                                   \
      } }

  #define COMPUTE(buf)                                                        \
    { _Pragma("unroll")                                                       \
      for (int ksub = 0; ksub < 2; ksub++){                                   \
        int rs = ksub ? rdSlot1 : rdSlot0;                                    \
        short8 fah[4], fal[4], fbh[4], fbl[4];                                \
        _Pragma("unroll")                                                     \
        for (int mi = 0; mi < 4; mi++){                                       \
          fah[mi] = *(const short8*)&lds[buf][0][(wm + mi*16 + fr)*64 + rs];  \
          fal[mi] = *(const short8*)&lds[buf][1][(wm + mi*16 + fr)*64 + rs];  \
          fbh[mi] = *(const short8*)&lds[buf][2][(wn + mi*16 + fr)*64 + rs];  \
          fbl[mi] = *(const short8*)&lds[buf][3][(wn + mi*16 + fr)*64 + rs];  \
        }                                                                     \
        _Pragma("unroll")                                                     \
        for (int mi = 0; mi < 4; mi++){                                       \
          _Pragma("unroll")                                                   \
          for (int ni = 0; ni < 4; ni++){                                     \
            acc[mi][ni] = __builtin_amdgcn_mfma_f32_16x16x32_bf16(fah[mi], fbh[ni], acc[mi][ni], 0,0,0); \
            acc[mi][ni] = __builtin_amdgcn_mfma_f32_16x16x32_bf16(fah[mi], fbl[ni], acc[mi][ni], 0,0,0); \
            acc[mi][ni] = __builtin_amdgcn_mfma_f32_16x16x32_bf16(fal[mi], fbh[ni], acc[mi][ni], 0,0,0); \
          }                                                                   \
        } } }

  STAGE(0, 0)
  int cur = 0;
  for (int k0 = 0; k0 + 64 < KB; k0 += 64, cur ^= 1){
    STAGE(cur^1, k0 + 64)
    asm volatile("s_waitcnt vmcnt(16)" ::: "memory");   // wait only cur's 16 loads
    __builtin_amdgcn_sched_barrier(0);
    __builtin_amdgcn_s_barrier();
    __builtin_amdgcn_sched_barrier(0);
    COMPUTE(cur)
    __builtin_amdgcn_sched_barrier(0);
    __builtin_amdgcn_s_barrier();                       // reads done -> next overwrite ok
  }
  asm volatile("s_waitcnt vmcnt(0)" ::: "memory");
  __builtin_amdgcn_sched_barrier(0);
  __builtin_amdgcn_s_barrier();
  __builtin_amdgcn_sched_barrier(0);
  COMPUTE(cur)

  #undef STAGE
  #undef COMPUTE

  int cr = (lane >> 4) * 4, cc = lane & 15;
  if (SPLITOUT){
    u16* Cb = (u16*)Cout + (size_t)z * cStride;
    const float scale = 0.03125f;   // 1/sqrt(1024)
    #pragma unroll
    for (int mi = 0; mi < 4; mi++){
      int gr = bx*128 + wm + mi*16 + cr;
      #pragma unroll
      for (int ni = 0; ni < 4; ni++){
        int gc = by*128 + wn + ni*16 + cc;
        #pragma unroll
        for (int rr = 0; rr < 4; rr++){
          float x = acc[mi][ni][rr] * scale;
          u16 h = f2bf(x);
          u16 l = f2bf(x - bf2f(h));
          size_t off = (size_t)(gr + rr) * (2*N_) + gc;
          Cb[off]      = h;
          Cb[off + N_] = l;
        }
      }
    }
  } else {
    float* Cb = (float*)Cout + (size_t)z * cStride;
    #pragma unroll
    for (int mi = 0; mi < 4; mi++){
      int gr = bx*128 + wm + mi*16 + cr;
      #pragma unroll
      for (int ni = 0; ni < 4; ni++){
        int gc = by*128 + wn + ni*16 + cc;
        #pragma unroll
        for (int rr = 0; rr < 4; rr++){
          Cb[(size_t)(gr + rr) * N_ + gc] = acc[mi][ni][rr];
        }
      }
    }
  }
}

// ---------- row softmax over D=1024, in place on d_out ----------
__global__ __launch_bounds__(256) void k_softmax(float* __restrict__ O){
  float* p = O + (size_t)blockIdx.x * DIM;
  int t = threadIdx.x;
  int lane = t & 63, wave = t >> 6;
  f32x4 v = *(f32x4*)(p + t*4);
  float m = fmaxf(fmaxf(v[0], v[1]), fmaxf(v[2], v[3]));
  #pragma unroll
  for (int o = 32; o > 0; o >>= 1) m = fmaxf(m, __shfl_xor(m, o));
  __shared__ float rmax[4], rsum[4];
  if (lane == 0) rmax[wave] = m;
  __syncthreads();
  m = fmaxf(fmaxf(rmax[0], rmax[1]), fmaxf(rmax[2], rmax[3]));
  float e0 = expf(v[0]-m), e1 = expf(v[1]-m), e2 = expf(v[2]-m), e3 = expf(v[3]-m);
  float s = e0 + e1 + e2 + e3;
  #pragma unroll
  for (int o = 32; o > 0; o >>= 1) s += __shfl_xor(s, o);
  if (lane == 0) rsum[wave] = s;
  __syncthreads();
  s = rsum[0] + rsum[1] + rsum[2] + rsum[3];
  float inv = 1.0f / s;
  f32x4 rv = { e0*inv, e1*inv, e2*inv, e3*inv };
  *(f32x4*)(p + t*4) = rv;
}

extern "C" void kernel_launch(void* const* d_in, const int* in_sizes, int n_in,
                              void* d_out, int out_size, void* d_ws, size_t ws_size,
                              hipStream_t stream){
  const float* Q = (const float*)d_in[0];
  const float* K = (const float*)d_in[1];
  const float* V = (const float*)d_in[2];
  float* Out = (float*)d_out;
  u16* w = (u16*)d_ws;

  const size_t QsB = (size_t)SEQ * (2*DIM);
  const size_t KtB = (size_t)DIM * (2*SEQ);
  const size_t VtB = KtB;
  const size_t WsB = (size_t)DIM * (2*DIM);

  dim3 blk(256);
  dim3 cgrid(SEQ/64, DIM/64, 8);

  const size_t need1 = 8 * (QsB + KtB + VtB + WsB) * sizeof(u16);  // ~235 MB
  const size_t need2 = 8 * (KtB + VtB + WsB) * sizeof(u16);        // ~168 MB

  if (ws_size >= need1){
    u16* Qs = w;
    u16* Kt = Qs + 8*QsB;
    u16* Vt = Kt + 8*KtB;
    u16* Ws = Vt + 8*VtB;
    k_split<<<dim3(2048), blk, 0, stream>>>(Q, Qs, 8*SEQ*(DIM/4));
    k_convert_vt<<<cgrid, blk, 0, stream>>>(K, Kt);
    k_convert_vt<<<cgrid, blk, 0, stream>>>(V, Vt);
    // GEMM-A: Wt = (V^T K)/32 -> split u16 [1024][2048]/batch.  grid 8x8x8 = 512
    k_gemm<DIM, SEQ, 1, 8, 2, 4><<<dim3(512), blk, 0, stream>>>(Vt, Kt, Ws, VtB, KtB, WsB);
    // GEMM-B: O = Qs * Wt^T -> fp32 [2048][1024]/batch.  grid 16x8x8 = 1024
    k_gemm<DIM, DIM, 0, 16, 4, 4><<<dim3(1024), blk, 0, stream>>>(Qs, Ws, Out, QsB, WsB, (size_t)SEQ*DIM);
  } else if (ws_size >= need2){
    u16* Kt = w;
    u16* Vt = Kt + 8*KtB;
    u16* Ws = Vt + 8*VtB;
    u16* Qs = w;                         // reuses Kt/Vt region after GEMM-A (stream-ordered)
    k_convert_vt<<<cgrid, blk, 0, stream>>>(K, Kt);
    k_convert_vt<<<cgrid, blk, 0, stream>>>(V, Vt);
    k_gemm<DIM, SEQ, 1, 8, 2, 4><<<dim3(512), blk, 0, stream>>>(Vt, Kt, Ws, VtB, KtB, WsB);
    k_split<<<dim3(2048), blk, 0, stream>>>(Q, Qs, 8*SEQ*(DIM/4));
    k_gemm<DIM, DIM, 0, 16, 4, 4><<<dim3(1024), blk, 0, stream>>>(Qs, Ws, Out, QsB, WsB, (size_t)SEQ*DIM);
  } else {
    // per-batch fallback
    u16* Qs = w;
    u16* Kt = Qs + QsB;
    u16* Vt = Kt + KtB;
    u16* Ws = Vt + VtB;
    dim3 cg1(SEQ/64, DIM/64, 1);
    for (int b = 0; b < BATCH; b++){
      const size_t inOff = (size_t)b * SEQ * DIM;
      k_split<<<dim3(1024), blk, 0, stream>>>(Q + inOff, Qs, SEQ*(DIM/4));
      k_convert_vt<<<cg1, blk, 0, stream>>>(K + inOff, Kt);
      k_convert_vt<<<cg1, blk, 0, stream>>>(V + inOff, Vt);
      k_gemm<DIM, SEQ, 1, 8, 2, 4><<<dim3(64), blk, 0, stream>>>(Vt, Kt, Ws, VtB, KtB, WsB);
      k_gemm<DIM, DIM, 0, 16, 4, 4><<<dim3(128), blk, 0, stream>>>(Qs, Ws, Out + inOff, QsB, WsB, (size_t)SEQ*DIM);
    }
  }
  k_softmax<<<dim3(BATCH*SEQ), blk, 0, stream>>>(Out);
}

// Round 6
// 309.429 us; speedup vs baseline: 1.1536x; 1.1536x over previous
//
#include <hip/hip_runtime.h>
#include <hip/hip_bf16.h>
#include <stdint.h>

#define BATCH 8
#define SEQ   2048
#define DIM   1024

typedef unsigned short u16;
typedef __attribute__((ext_vector_type(8))) short short8;
typedef __attribute__((ext_vector_type(4))) float f32x4;
typedef __attribute__((ext_vector_type(4))) unsigned short us4;

__device__ __forceinline__ u16 f2bf(float x){
  union { float f; uint32_t u; } c; c.f = x;
  uint32_t u = c.u;
  uint32_t r = u + 0x7fffu + ((u >> 16) & 1u);
  return (u16)(r >> 16);
}
__device__ __forceinline__ float bf2f(u16 s){
  union { uint32_t u; float f; } c; c.u = ((uint32_t)s) << 16;
  return c.f;
}

// async global->LDS, 16B per lane. LDS dest is wave-uniform base + lane*16.
__device__ __forceinline__ void gload16(const void* g, void* l){
  __builtin_amdgcn_global_load_lds(
      (const __attribute__((address_space(1))) void*)g,
      (__attribute__((address_space(3))) void*)l, 16, 0, 0);
}

// ---------- split fp32 [R][1024] -> u16 [R][2048] rows packed [hi|lo] ----------
__global__ __launch_bounds__(256) void k_split(const float* __restrict__ src,
                                               u16* __restrict__ dst, int nchunk){
  for (int i = blockIdx.x*blockDim.x + threadIdx.x; i < nchunk; i += gridDim.x*blockDim.x){
    int r = i >> 8;
    int c = (i & 255) << 2;
    f32x4 v = *(const f32x4*)(src + (size_t)r*DIM + c);
    us4 h, l;
    #pragma unroll
    for (int j = 0; j < 4; j++){
      u16 hh = f2bf(v[j]);
      h[j] = hh;
      l[j] = f2bf(v[j] - bf2f(hh));
    }
    u16* d = dst + (size_t)r*(2*DIM) + c;
    *(us4*)d         = h;
    *(us4*)(d + DIM) = l;
  }
}

// ---------- transpose + split (K and V in one launch): z<8 -> K->Kt, z>=8 -> V->Vt ----------
__global__ __launch_bounds__(256) void k_convert_kv(const float* __restrict__ K,
                                                    const float* __restrict__ V,
                                                    u16* __restrict__ Kt,
                                                    u16* __restrict__ Vt){
  __shared__ float tile[64][65];
  int z = blockIdx.z;
  const float* Src = (z < 8 ? K : V);
  u16* Dst = (z < 8 ? Kt : Vt);
  int zb = z & 7;
  const float* Vb = Src + (size_t)zb * SEQ * DIM;
  u16* Vtb = Dst + (size_t)zb * DIM * (2*SEQ);
  int s0 = blockIdx.x * 64, d0 = blockIdx.y * 64;
  int t = threadIdx.x;
  int rs = t >> 4;
  int cd = (t & 15) * 4;
  #pragma unroll
  for (int i = 0; i < 4; i++){
    int s = rs + i*16;
    f32x4 v = *(const f32x4*)(Vb + (size_t)(s0 + s)*DIM + d0 + cd);
    tile[s][cd+0] = v[0]; tile[s][cd+1] = v[1];
    tile[s][cd+2] = v[2]; tile[s][cd+3] = v[3];
  }
  __syncthreads();
  int dl = t >> 4;
  int sl = (t & 15) * 4;
  #pragma unroll
  for (int i = 0; i < 4; i++){
    int d = dl + i*16;
    us4 h, l;
    #pragma unroll
    for (int j = 0; j < 4; j++){
      float x = tile[sl+j][d];
      u16 hh = f2bf(x);
      h[j] = hh;
      l[j] = f2bf(x - bf2f(hh));
    }
    size_t off = (size_t)(d0 + d) * (2*SEQ) + s0 + sl;
    *(us4*)(Vtb + off)       = h;
    *(us4*)(Vtb + off + SEQ) = l;
  }
}

// ---------- GEMM C = A * B^T, hi/lo split, BK=32, dbuf prefetch-1, 2 blocks/CU ----------
// A: [M][2*KB] u16 rows packed [hi|lo]; B: [N_][2*KB] u16 packed [hi|lo].
// LDS per row = 32 elems = 4 x 16B slots; slot swizzle: lds_slot = g ^ ((row>>1)&3).
// Staged via pre-swizzled global source (LDS linear), read with matching XOR.
// SPLITOUT=1: C=acc/32 split u16 [M][2*N_]; SPLITOUT=0: C=acc fp32 [M][N_].
template<int N_, int KB, int SPLITOUT, int BX, int RX, int RY>
__global__ __launch_bounds__(256,2) void k_gemm(const u16* __restrict__ A,
                                                const u16* __restrict__ B,
                                                void* __restrict__ Cout,
                                                size_t aStride, size_t bStride, size_t cStride){
  constexpr int LA = 2*KB;
  // [buf][array: Ah,Al,Bh,Bl][128 rows x 32 elems]  = 64 KB total
  __shared__ __align__(16) u16 lds[2][4][128*32];

  int orig = blockIdx.x;
  int xcd = orig & 7;
  int idx = orig >> 3;
  constexpr int RN = RX * RY;
  int z  = idx / RN;
  int r  = idx % RN;
  int bx = (xcd % (BX/RX)) * RX + (r % RX);
  int by = (xcd / (BX/RX)) * RY + (r / RX);

  const u16* Ab = A + (size_t)z * aStride;
  const u16* Bb = B + (size_t)z * bStride;

  int t = threadIdx.x, lane = t & 63, w = t >> 6;
  int wm = (w & 1) * 64, wn = (w >> 1) * 64;
  int fr = lane & 15;

  // staging: chunk c = w*2+o covers rows [c*16, c*16+16); lane -> row c*16+(lane>>2),
  // LDS slot (lane&3); fetches global slot (lane&3)^((lane>>3)&3)  [row>>1 parity bits]
  int srow    = lane >> 2;
  int srcSlot = ((lane & 3) ^ ((lane >> 3) & 3)) * 8;

  const u16* aBase = Ab + ((size_t)bx*128) * LA + srcSlot;
  const u16* bBase = Bb + ((size_t)by*128) * LA + srcSlot;

  // fragment read: global slot kgi=(lane>>4) at row wm+mi*16+fr -> LDS slot kgi^((fr>>1)&3)
  int rdSlot = (((lane >> 4) ^ ((fr >> 1) & 3))) * 8;

  f32x4 acc[4][4] = {};

  #define STAGE(buf, k0)                                                      \
    { _Pragma("unroll")                                                       \
      for (int o = 0; o < 2; o++){                                            \
        int c = w*2 + o;                                                      \
        size_t rOff = (size_t)(c*16 + srow) * LA + (k0);                      \
        const u16* ga = aBase + rOff;                                         \
        const u16* gb = bBase + rOff;                                         \
        int le = c * 512;                                                     \
        gload16(ga,      &lds[buf][0][le]);                                   \
        gload16(ga + KB, &lds[buf][1][le]);                                   \
        gload16(gb,      &lds[buf][2][le]);                                   \
        gload16(gb + KB, &lds[buf][3][le]);                                   \
      } }

  #define COMPUTE(buf)                                                        \
    { short8 fah[4], fal[4], fbh[4], fbl[4];                                  \
      _Pragma("unroll")                                                       \
      for (int mi = 0; mi < 4; mi++){                                         \
        fah[mi] = *(const short8*)&lds[buf][0][(wm + mi*16 + fr)*32 + rdSlot];\
        fal[mi] = *(const short8*)&lds[buf][1][(wm + mi*16 + fr)*32 + rdSlot];\
        fbh[mi] = *(const short8*)&lds[buf][2][(wn + mi*16 + fr)*32 + rdSlot];\
        fbl[mi] = *(const short8*)&lds[buf][3][(wn + mi*16 + fr)*32 + rdSlot];\
      }                                                                       \
      _Pragma("unroll")                                                       \
      for (int mi = 0; mi < 4; mi++){                                         \
        _Pragma("unroll")                                                     \
        for (int ni = 0; ni < 4; ni++){                                       \
          acc[mi][ni] = __builtin_amdgcn_mfma_f32_16x16x32_bf16(fah[mi], fbh[ni], acc[mi][ni], 0,0,0); \
          acc[mi][ni] = __builtin_amdgcn_mfma_f32_16x16x32_bf16(fah[mi], fbl[ni], acc[mi][ni], 0,0,0); \
          acc[mi][ni] = __builtin_amdgcn_mfma_f32_16x16x32_bf16(fal[mi], fbh[ni], acc[mi][ni], 0,0,0); \
        }                                                                     \
      } }

  STAGE(0, 0)
  int cur = 0;
  for (int k0 = 0; k0 + 32 < KB; k0 += 32, cur ^= 1){
    STAGE(cur^1, k0 + 32)
    asm volatile("s_waitcnt vmcnt(8)" ::: "memory");   // drain only cur's 8 loads
    __builtin_amdgcn_sched_barrier(0);
    __builtin_amdgcn_s_barrier();
    __builtin_amdgcn_sched_barrier(0);
    COMPUTE(cur)
    __builtin_amdgcn_sched_barrier(0);
    __builtin_amdgcn_s_barrier();                      // all reads done -> overwrite ok
  }
  asm volatile("s_waitcnt vmcnt(0)" ::: "memory");
  __builtin_amdgcn_sched_barrier(0);
  __builtin_amdgcn_s_barrier();
  __builtin_amdgcn_sched_barrier(0);
  COMPUTE(cur)

  #undef STAGE
  #undef COMPUTE

  int cr = (lane >> 4) * 4, cc = lane & 15;
  if (SPLITOUT){
    u16* Cb = (u16*)Cout + (size_t)z * cStride;
    const float scale = 0.03125f;   // 1/sqrt(1024)
    #pragma unroll
    for (int mi = 0; mi < 4; mi++){
      int gr = bx*128 + wm + mi*16 + cr;
      #pragma unroll
      for (int ni = 0; ni < 4; ni++){
        int gc = by*128 + wn + ni*16 + cc;
        #pragma unroll
        for (int rr = 0; rr < 4; rr++){
          float x = acc[mi][ni][rr] * scale;
          u16 h = f2bf(x);
          u16 l = f2bf(x - bf2f(h));
          size_t off = (size_t)(gr + rr) * (2*N_) + gc;
          Cb[off]      = h;
          Cb[off + N_] = l;
        }
      }
    }
  } else {
    float* Cb = (float*)Cout + (size_t)z * cStride;
    #pragma unroll
    for (int mi = 0; mi < 4; mi++){
      int gr = bx*128 + wm + mi*16 + cr;
      #pragma unroll
      for (int ni = 0; ni < 4; ni++){
        int gc = by*128 + wn + ni*16 + cc;
        #pragma unroll
        for (int rr = 0; rr < 4; rr++){
          Cb[(size_t)(gr + rr) * N_ + gc] = acc[mi][ni][rr];
        }
      }
    }
  }
}

// ---------- row softmax over D=1024, in place on d_out ----------
__global__ __launch_bounds__(256) void k_softmax(float* __restrict__ O){
  float* p = O + (size_t)blockIdx.x * DIM;
  int t = threadIdx.x;
  int lane = t & 63, wave = t >> 6;
  f32x4 v = *(f32x4*)(p + t*4);
  float m = fmaxf(fmaxf(v[0], v[1]), fmaxf(v[2], v[3]));
  #pragma unroll
  for (int o = 32; o > 0; o >>= 1) m = fmaxf(m, __shfl_xor(m, o));
  __shared__ float rmax[4], rsum[4];
  if (lane == 0) rmax[wave] = m;
  __syncthreads();
  m = fmaxf(fmaxf(rmax[0], rmax[1]), fmaxf(rmax[2], rmax[3]));
  float e0 = expf(v[0]-m), e1 = expf(v[1]-m), e2 = expf(v[2]-m), e3 = expf(v[3]-m);
  float s = e0 + e1 + e2 + e3;
  #pragma unroll
  for (int o = 32; o > 0; o >>= 1) s += __shfl_xor(s, o);
  if (lane == 0) rsum[wave] = s;
  __syncthreads();
  s = rsum[0] + rsum[1] + rsum[2] + rsum[3];
  float inv = 1.0f / s;
  f32x4 rv = { e0*inv, e1*inv, e2*inv, e3*inv };
  *(f32x4*)(p + t*4) = rv;
}

extern "C" void kernel_launch(void* const* d_in, const int* in_sizes, int n_in,
                              void* d_out, int out_size, void* d_ws, size_t ws_size,
                              hipStream_t stream){
  const float* Q = (const float*)d_in[0];
  const float* K = (const float*)d_in[1];
  const float* V = (const float*)d_in[2];
  float* Out = (float*)d_out;
  u16* w = (u16*)d_ws;

  const size_t QsB = (size_t)SEQ * (2*DIM);
  const size_t KtB = (size_t)DIM * (2*SEQ);
  const size_t VtB = KtB;
  const size_t WsB = (size_t)DIM * (2*DIM);

  dim3 blk(256);
  dim3 cgrid(SEQ/64, DIM/64, 16);   // z<8: K, z>=8: V

  const size_t need1 = 8 * (QsB + KtB + VtB + WsB) * sizeof(u16);  // ~235 MB
  const size_t need2 = 8 * (KtB + VtB + WsB) * sizeof(u16);        // ~168 MB

  if (ws_size >= need1){
    u16* Qs = w;
    u16* Kt = Qs + 8*QsB;
    u16* Vt = Kt + 8*KtB;
    u16* Ws = Vt + 8*VtB;
    k_split<<<dim3(2048), blk, 0, stream>>>(Q, Qs, 8*SEQ*(DIM/4));
    k_convert_kv<<<cgrid, blk, 0, stream>>>(K, V, Kt, Vt);
    // GEMM-A: Wt = (V^T K)/32 -> split u16 [1024][2048]/batch.  grid 8x8x8 = 512
    k_gemm<DIM, SEQ, 1, 8, 2, 4><<<dim3(512), blk, 0, stream>>>(Vt, Kt, Ws, VtB, KtB, WsB);
    // GEMM-B: O = Qs * Wt^T -> fp32 [2048][1024]/batch.  grid 16x8x8 = 1024
    k_gemm<DIM, DIM, 0, 16, 4, 4><<<dim3(1024), blk, 0, stream>>>(Qs, Ws, Out, QsB, WsB, (size_t)SEQ*DIM);
  } else if (ws_size >= need2){
    u16* Kt = w;
    u16* Vt = Kt + 8*KtB;
    u16* Ws = Vt + 8*VtB;
    u16* Qs = w;                         // reuses Kt/Vt region after GEMM-A (stream-ordered)
    k_convert_kv<<<cgrid, blk, 0, stream>>>(K, V, Kt, Vt);
    k_gemm<DIM, SEQ, 1, 8, 2, 4><<<dim3(512), blk, 0, stream>>>(Vt, Kt, Ws, VtB, KtB, WsB);
    k_split<<<dim3(2048), blk, 0, stream>>>(Q, Qs, 8*SEQ*(DIM/4));
    k_gemm<DIM, DIM, 0, 16, 4, 4><<<dim3(1024), blk, 0, stream>>>(Qs, Ws, Out, QsB, WsB, (size_t)SEQ*DIM);
  } else {
    // per-batch fallback (convert kernel used with K=V slices per batch)
    u16* Qs = w;
    u16* Kt = Qs + QsB;
    u16* Vt = Kt + KtB;
    u16* Ws = Vt + VtB;
    dim3 cg1(SEQ/64, DIM/64, 2);
    for (int b = 0; b < BATCH; b++){
      const size_t inOff = (size_t)b * SEQ * DIM;
      k_split<<<dim3(1024), blk, 0, stream>>>(Q + inOff, Qs, SEQ*(DIM/4));
      // z=0 -> K batch0 of (K+inOff); z=8.. not used with z-dim 2: use two single launches
      k_convert_kv<<<dim3(SEQ/64, DIM/64, 1), blk, 0, stream>>>(K + inOff, K + inOff, Kt, Kt);
      k_convert_kv<<<dim3(SEQ/64, DIM/64, 1), blk, 0, stream>>>(V + inOff, V + inOff, Vt, Vt);
      k_gemm<DIM, SEQ, 1, 8, 2, 4><<<dim3(64), blk, 0, stream>>>(Vt, Kt, Ws, VtB, KtB, WsB);
      k_gemm<DIM, DIM, 0, 16, 4, 4><<<dim3(128), blk, 0, stream>>>(Qs, Ws, Out + inOff, QsB, WsB, (size_t)SEQ*DIM);
    }
  }
  k_softmax<<<dim3(BATCH*SEQ), blk, 0, stream>>>(Out);
}

// Round 7
// 285.440 us; speedup vs baseline: 1.2506x; 1.0840x over previous
//
#include <hip/hip_runtime.h>
#include <hip/hip_bf16.h>
#include <stdint.h>

#define BATCH 8
#define SEQ   2048
#define DIM   1024

typedef unsigned short u16;
typedef __attribute__((ext_vector_type(8))) short short8;
typedef __attribute__((ext_vector_type(4))) float f32x4;
typedef __attribute__((ext_vector_type(4))) unsigned short us4;

__device__ __forceinline__ u16 f2bf(float x){
  union { float f; uint32_t u; } c; c.f = x;
  uint32_t u = c.u;
  uint32_t r = u + 0x7fffu + ((u >> 16) & 1u);
  return (u16)(r >> 16);
}
__device__ __forceinline__ float bf2f(u16 s){
  union { uint32_t u; float f; } c; c.u = ((uint32_t)s) << 16;
  return c.f;
}

__device__ __forceinline__ void gload16(const void* g, void* l){
  __builtin_amdgcn_global_load_lds(
      (const __attribute__((address_space(1))) void*)g,
      (__attribute__((address_space(3))) void*)l, 16, 0, 0);
}

// ---------- split fp32 [R][1024] -> u16 [R][2048] rows packed [hi|lo] ----------
__global__ __launch_bounds__(256) void k_split(const float* __restrict__ src,
                                               u16* __restrict__ dst, int nchunk){
  for (int i = blockIdx.x*blockDim.x + threadIdx.x; i < nchunk; i += gridDim.x*blockDim.x){
    int r = i >> 8;
    int c = (i & 255) << 2;
    f32x4 v = *(const f32x4*)(src + (size_t)r*DIM + c);
    us4 h, l;
    #pragma unroll
    for (int j = 0; j < 4; j++){
      u16 hh = f2bf(v[j]);
      h[j] = hh;
      l[j] = f2bf(v[j] - bf2f(hh));
    }
    u16* d = dst + (size_t)r*(2*DIM) + c;
    *(us4*)d         = h;
    *(us4*)(d + DIM) = l;
  }
}

// ---------- transpose + split (K and V in one launch): z<8 -> K->Kt, z>=8 -> V->Vt ----------
__global__ __launch_bounds__(256) void k_convert_kv(const float* __restrict__ K,
                                                    const float* __restrict__ V,
                                                    u16* __restrict__ Kt,
                                                    u16* __restrict__ Vt){
  __shared__ float tile[64][65];
  int z = blockIdx.z;
  const float* Src = (z < 8 ? K : V);
  u16* Dst = (z < 8 ? Kt : Vt);
  int zb = z & 7;
  const float* Vb = Src + (size_t)zb * SEQ * DIM;
  u16* Vtb = Dst + (size_t)zb * DIM * (2*SEQ);
  int s0 = blockIdx.x * 64, d0 = blockIdx.y * 64;
  int t = threadIdx.x;
  int rs = t >> 4;
  int cd = (t & 15) * 4;
  #pragma unroll
  for (int i = 0; i < 4; i++){
    int s = rs + i*16;
    f32x4 v = *(const f32x4*)(Vb + (size_t)(s0 + s)*DIM + d0 + cd);
    tile[s][cd+0] = v[0]; tile[s][cd+1] = v[1];
    tile[s][cd+2] = v[2]; tile[s][cd+3] = v[3];
  }
  __syncthreads();
  int dl = t >> 4;
  int sl = (t & 15) * 4;
  #pragma unroll
  for (int i = 0; i < 4; i++){
    int d = dl + i*16;
    us4 h, l;
    #pragma unroll
    for (int j = 0; j < 4; j++){
      float x = tile[sl+j][d];
      u16 hh = f2bf(x);
      h[j] = hh;
      l[j] = f2bf(x - bf2f(hh));
    }
    size_t off = (size_t)(d0 + d) * (2*SEQ) + s0 + sl;
    *(us4*)(Vtb + off)       = h;
    *(us4*)(Vtb + off + SEQ) = l;
  }
}

// ---------- 256x256 8-wave phase-split GEMM, hi/lo split operands, fp32 out ----------
// A: rows [hi(KROW)|lo(KROW)]; B same. C fp32, ld=1024. K processed per block = 1024.
// SPLITK=1: z -> (kh = z>>3, zb = z&7), K-offset kh*1024. Grid must be multiple of 8.
template<int KROW, int SPLITK, int TPZX, int TPZY>
__global__ __launch_bounds__(512,1) void k_gemm8(const u16* __restrict__ A,
                                                 const u16* __restrict__ B,
                                                 float* __restrict__ C,
                                                 size_t aStride, size_t bStride, size_t cStride){
  constexpr int LA = 2*KROW;
  constexpr int NT = 1024/32;     // 32 K-tiles
  __shared__ __align__(16) u16 lds[2][4][256*32];   // [buf][Ah,Al,Bh,Bl] = 128 KB

  int xcd = blockIdx.x & 7;
  int idx = blockIdx.x >> 3;
  int nPerX = gridDim.x >> 3;
  int gid = xcd * nPerX + idx;
  constexpr int TPZ = TPZX*TPZY;
  int z  = gid / TPZ;
  int rm = gid % TPZ;
  int bx = rm % TPZX;
  int by = rm / TPZX;

  int zb = SPLITK ? (z & 7) : z;
  int kh = SPLITK ? (z >> 3) : 0;

  const u16* Ab = A + (size_t)zb * aStride + (size_t)kh * 1024;
  const u16* Bb = B + (size_t)zb * bStride + (size_t)kh * 1024;
  float* Cb = C + (size_t)z * cStride;

  int t0 = threadIdx.x, lane = t0 & 63, wv = t0 >> 6;
  int wm = (wv >> 2) * 128, wn = (wv & 3) * 64;
  int fr = lane & 15;
  int rdSlot = ((lane >> 4) ^ ((fr >> 1) & 3)) * 8;
  int srow = lane >> 2;
  int srcSlot = ((lane & 3) ^ ((lane >> 3) & 3)) * 8;

  const u16* aB = Ab + ((size_t)bx*256) * LA + srcSlot;
  const u16* bB = Bb + ((size_t)by*256) * LA + srcSlot;
  int ldsB0 = wv*512;

  f32x4 acc[8][4] = {};
  short8 fah[4], fal[4], fbh0[2], fbl0[2], fbh1[2], fbl1[2];

  #define STAGE8(buf, t32)                                                    \
    { _Pragma("unroll")                                                       \
      for (int hf = 0; hf < 2; hf++){                                         \
        size_t ro = (size_t)(wv*16 + hf*128 + srow) * LA + (size_t)(t32)*32;  \
        const u16* ga = aB + ro;                                              \
        const u16* gb = bB + ro;                                              \
        int lo = ldsB0 + hf*4096;                                             \
        gload16(ga,        &lds[buf][0][lo]);                                 \
        gload16(ga + KROW, &lds[buf][1][lo]);                                 \
        gload16(gb,        &lds[buf][2][lo]);                                 \
        gload16(gb + KROW, &lds[buf][3][lo]);                                 \
      } }

  #define LOAD_A(buf, h)                                                      \
    { _Pragma("unroll")                                                       \
      for (int q = 0; q < 4; q++){                                            \
        int ra = (wm + ((h)*4+q)*16 + fr)*32 + rdSlot;                        \
        fah[q] = *(const short8*)&lds[buf][0][ra];                            \
        fal[q] = *(const short8*)&lds[buf][1][ra];                            \
      } }
  #define LOAD_B0(buf)                                                        \
    { _Pragma("unroll")                                                       \
      for (int q = 0; q < 2; q++){                                            \
        int rb = (wn + q*16 + fr)*32 + rdSlot;                                \
        fbh0[q] = *(const short8*)&lds[buf][2][rb];                           \
        fbl0[q] = *(const short8*)&lds[buf][3][rb];                           \
      } }
  #define LOAD_B1(buf)                                                        \
    { _Pragma("unroll")                                                       \
      for (int q = 0; q < 2; q++){                                            \
        int rb = (wn + (2+q)*16 + fr)*32 + rdSlot;                            \
        fbh1[q] = *(const short8*)&lds[buf][2][rb];                           \
        fbl1[q] = *(const short8*)&lds[buf][3][rb];                           \
      } }

  #define MFMA_Q(h, bh, bl, nb)                                               \
    { _Pragma("unroll")                                                       \
      for (int q = 0; q < 4; q++){                                            \
        _Pragma("unroll")                                                     \
        for (int j = 0; j < 2; j++){                                          \
          f32x4 a0 = acc[(h)*4+q][(nb)+j];                                    \
          a0 = __builtin_amdgcn_mfma_f32_16x16x32_bf16(fah[q], bh[j], a0, 0,0,0); \
          a0 = __builtin_amdgcn_mfma_f32_16x16x32_bf16(fah[q], bl[j], a0, 0,0,0); \
          a0 = __builtin_amdgcn_mfma_f32_16x16x32_bf16(fal[q], bh[j], a0, 0,0,0); \
          acc[(h)*4+q][(nb)+j] = a0;                                          \
        } } }

  #define BARR()  __builtin_amdgcn_s_barrier()
  #define LGKM0() { asm volatile("s_waitcnt lgkmcnt(0)" ::: "memory"); __builtin_amdgcn_sched_barrier(0); }
  #define VMC0()  { asm volatile("s_waitcnt vmcnt(0)" ::: "memory"); __builtin_amdgcn_sched_barrier(0); }

  STAGE8(0, 0)
  VMC0()
  BARR();

  for (int t = 0; t < NT; t++){
    int buf = t & 1;
    // phase 1: burst-issue next tile's 8 loads, read A0 + B0, compute A0xB0
    if (t+1 < NT) STAGE8(buf^1, t+1)
    LOAD_A(buf, 0) LOAD_B0(buf)
    BARR(); LGKM0()
    __builtin_amdgcn_s_setprio(1); MFMA_Q(0, fbh0, fbl0, 0) __builtin_amdgcn_s_setprio(0);
    BARR();
    // phase 2: read B1, compute A0xB1
    LOAD_B1(buf)
    BARR(); LGKM0()
    __builtin_amdgcn_s_setprio(1); MFMA_Q(0, fbh1, fbl1, 2) __builtin_amdgcn_s_setprio(0);
    BARR();
    // phase 3: read A1, compute A1xB1
    LOAD_A(buf, 1)
    BARR(); LGKM0()
    __builtin_amdgcn_s_setprio(1); MFMA_Q(1, fbh1, fbl1, 2) __builtin_amdgcn_s_setprio(0);
    BARR();
    // phase 4: no LDS reads (B0 retained in regs), compute A1xB0
    __builtin_amdgcn_s_setprio(1); MFMA_Q(1, fbh0, fbl0, 0) __builtin_amdgcn_s_setprio(0);
    if (t+1 < NT) VMC0()
    BARR();
  }

  #undef STAGE8
  #undef LOAD_A
  #undef LOAD_B0
  #undef LOAD_B1
  #undef MFMA_Q
  #undef BARR
  #undef LGKM0
  #undef VMC0

  int cr = (lane >> 4) * 4;
  #pragma unroll
  for (int mi = 0; mi < 8; mi++){
    int gr = bx*256 + wm + mi*16 + cr;
    #pragma unroll
    for (int ni = 0; ni < 4; ni++){
      int gc = by*256 + wn + ni*16 + fr;
      #pragma unroll
      for (int e = 0; e < 4; e++)
        Cb[(size_t)(gr + e) * 1024 + gc] = acc[mi][ni][e];
    }
  }
}

// ---------- reduce split-K partials + scale + split to u16 [hi|lo] ----------
__global__ __launch_bounds__(256) void k_reduce_split(const float* __restrict__ P,
                                                      u16* __restrict__ Ws){
  int i = blockIdx.x*256 + threadIdx.x;   // 4-elem chunk id
  int rg = i >> 8;                        // zb*1024 + d  (8192 rows)
  int c  = (i & 255) * 4;
  f32x4 a = *(const f32x4*)(P + (size_t)rg*1024 + c);
  f32x4 b = *(const f32x4*)(P + ((size_t)rg + 8192)*1024 + c);
  us4 h, l;
  #pragma unroll
  for (int j = 0; j < 4; j++){
    float x = (a[j] + b[j]) * 0.03125f;
    u16 hh = f2bf(x);
    h[j] = hh;
    l[j] = f2bf(x - bf2f(hh));
  }
  int zb = rg >> 10, d = rg & 1023;
  u16* Wb = Ws + (size_t)zb * ((size_t)DIM * 2*DIM);
  *(us4*)(Wb + (size_t)d*2048 + c)        = h;
  *(us4*)(Wb + (size_t)d*2048 + 1024 + c) = l;
}

// ---------- legacy 128x128 2-phase GEMM (fallback tiers) ----------
template<int N_, int KB, int SPLITOUT, int BX, int RX, int RY>
__global__ __launch_bounds__(256,2) void k_gemm2ph(const u16* __restrict__ A,
                                                   const u16* __restrict__ B,
                                                   void* __restrict__ Cout,
                                                   size_t aStride, size_t bStride, size_t cStride){
  constexpr int LA = 2*KB;
  __shared__ __align__(16) u16 lds[2][4][128*32];

  int orig = blockIdx.x;
  int xcd = orig & 7;
  int idx = orig >> 3;
  constexpr int RN = RX * RY;
  int z  = idx / RN;
  int r  = idx % RN;
  int bx = (xcd % (BX/RX)) * RX + (r % RX);
  int by = (xcd / (BX/RX)) * RY + (r / RX);

  const u16* Ab = A + (size_t)z * aStride;
  const u16* Bb = B + (size_t)z * bStride;

  int t = threadIdx.x, lane = t & 63, w = t >> 6;
  int wm = (w & 1) * 64, wn = (w >> 1) * 64;
  int fr = lane & 15;
  int srow    = lane >> 2;
  int srcSlot = ((lane & 3) ^ ((lane >> 3) & 3)) * 8;

  const u16* aBase = Ab + ((size_t)bx*128) * LA + srcSlot;
  const u16* bBase = Bb + ((size_t)by*128) * LA + srcSlot;
  int rdSlot = (((lane >> 4) ^ ((fr >> 1) & 3))) * 8;

  f32x4 acc[4][4] = {};

  #define STAGE(buf, k0)                                                      \
    { _Pragma("unroll")                                                       \
      for (int o = 0; o < 2; o++){                                            \
        int c = w*2 + o;                                                      \
        size_t rOff = (size_t)(c*16 + srow) * LA + (k0);                      \
        const u16* ga = aBase + rOff;                                         \
        const u16* gb = bBase + rOff;                                         \
        int le = c * 512;                                                     \
        gload16(ga,      &lds[buf][0][le]);                                   \
        gload16(ga + KB, &lds[buf][1][le]);                                   \
        gload16(gb,      &lds[buf][2][le]);                                   \
        gload16(gb + KB, &lds[buf][3][le]);                                   \
      } }

  #define COMPUTE(buf)                                                        \
    { short8 fah[4], fal[4], fbh[4], fbl[4];                                  \
      _Pragma("unroll")                                                       \
      for (int mi = 0; mi < 4; mi++){                                         \
        fah[mi] = *(const short8*)&lds[buf][0][(wm + mi*16 + fr)*32 + rdSlot];\
        fal[mi] = *(const short8*)&lds[buf][1][(wm + mi*16 + fr)*32 + rdSlot];\
        fbh[mi] = *(const short8*)&lds[buf][2][(wn + mi*16 + fr)*32 + rdSlot];\
        fbl[mi] = *(const short8*)&lds[buf][3][(wn + mi*16 + fr)*32 + rdSlot];\
      }                                                                       \
      _Pragma("unroll")                                                       \
      for (int mi = 0; mi < 4; mi++){                                         \
        _Pragma("unroll")                                                     \
        for (int ni = 0; ni < 4; ni++){                                       \
          acc[mi][ni] = __builtin_amdgcn_mfma_f32_16x16x32_bf16(fah[mi], fbh[ni], acc[mi][ni], 0,0,0); \
          acc[mi][ni] = __builtin_amdgcn_mfma_f32_16x16x32_bf16(fah[mi], fbl[ni], acc[mi][ni], 0,0,0); \
          acc[mi][ni] = __builtin_amdgcn_mfma_f32_16x16x32_bf16(fal[mi], fbh[ni], acc[mi][ni], 0,0,0); \
        }                                                                     \
      } }

  STAGE(0, 0)
  int cur = 0;
  for (int k0 = 0; k0 + 32 < KB; k0 += 32, cur ^= 1){
    STAGE(cur^1, k0 + 32)
    asm volatile("s_waitcnt vmcnt(8)" ::: "memory");
    __builtin_amdgcn_sched_barrier(0);
    __builtin_amdgcn_s_barrier();
    __builtin_amdgcn_sched_barrier(0);
    COMPUTE(cur)
    __builtin_amdgcn_sched_barrier(0);
    __builtin_amdgcn_s_barrier();
  }
  asm volatile("s_waitcnt vmcnt(0)" ::: "memory");
  __builtin_amdgcn_sched_barrier(0);
  __builtin_amdgcn_s_barrier();
  __builtin_amdgcn_sched_barrier(0);
  COMPUTE(cur)

  #undef STAGE
  #undef COMPUTE

  int cr = (lane >> 4) * 4, cc = lane & 15;
  if (SPLITOUT){
    u16* Cb = (u16*)Cout + (size_t)z * cStride;
    const float scale = 0.03125f;
    #pragma unroll
    for (int mi = 0; mi < 4; mi++){
      int gr = bx*128 + wm + mi*16 + cr;
      #pragma unroll
      for (int ni = 0; ni < 4; ni++){
        int gc = by*128 + wn + ni*16 + cc;
        #pragma unroll
        for (int rr = 0; rr < 4; rr++){
          float x = acc[mi][ni][rr] * scale;
          u16 h = f2bf(x);
          u16 l = f2bf(x - bf2f(h));
          size_t off = (size_t)(gr + rr) * (2*N_) + gc;
          Cb[off]      = h;
          Cb[off + N_] = l;
        }
      }
    }
  } else {
    float* Cb = (float*)Cout + (size_t)z * cStride;
    #pragma unroll
    for (int mi = 0; mi < 4; mi++){
      int gr = bx*128 + wm + mi*16 + cr;
      #pragma unroll
      for (int ni = 0; ni < 4; ni++){
        int gc = by*128 + wn + ni*16 + cc;
        #pragma unroll
        for (int rr = 0; rr < 4; rr++){
          Cb[(size_t)(gr + rr) * N_ + gc] = acc[mi][ni][rr];
        }
      }
    }
  }
}

// ---------- row softmax over D=1024, in place on d_out ----------
__global__ __launch_bounds__(256) void k_softmax(float* __restrict__ O){
  float* p = O + (size_t)blockIdx.x * DIM;
  int t = threadIdx.x;
  int lane = t & 63, wave = t >> 6;
  f32x4 v = *(f32x4*)(p + t*4);
  float m = fmaxf(fmaxf(v[0], v[1]), fmaxf(v[2], v[3]));
  #pragma unroll
  for (int o = 32; o > 0; o >>= 1) m = fmaxf(m, __shfl_xor(m, o));
  __shared__ float rmax[4], rsum[4];
  if (lane == 0) rmax[wave] = m;
  __syncthreads();
  m = fmaxf(fmaxf(rmax[0], rmax[1]), fmaxf(rmax[2], rmax[3]));
  float e0 = expf(v[0]-m), e1 = expf(v[1]-m), e2 = expf(v[2]-m), e3 = expf(v[3]-m);
  float s = e0 + e1 + e2 + e3;
  #pragma unroll
  for (int o = 32; o > 0; o >>= 1) s += __shfl_xor(s, o);
  if (lane == 0) rsum[wave] = s;
  __syncthreads();
  s = rsum[0] + rsum[1] + rsum[2] + rsum[3];
  float inv = 1.0f / s;
  f32x4 rv = { e0*inv, e1*inv, e2*inv, e3*inv };
  *(f32x4*)(p + t*4) = rv;
}

extern "C" void kernel_launch(void* const* d_in, const int* in_sizes, int n_in,
                              void* d_out, int out_size, void* d_ws, size_t ws_size,
                              hipStream_t stream){
  const float* Q = (const float*)d_in[0];
  const float* K = (const float*)d_in[1];
  const float* V = (const float*)d_in[2];
  float* Out = (float*)d_out;
  u16* w = (u16*)d_ws;

  const size_t QsB = (size_t)SEQ * (2*DIM);   // 4.19M u16 / batch
  const size_t KtB = (size_t)DIM * (2*SEQ);
  const size_t VtB = KtB;
  const size_t WsB = (size_t)DIM * (2*DIM);

  dim3 blk(256);
  dim3 cgrid(SEQ/64, DIM/64, 16);

  const size_t base2 = 8 * (KtB + VtB + WsB) * sizeof(u16);          // ~167.8 MB
  const size_t needA = base2 + (size_t)16*1024*1024*sizeof(float);   // ~234.9 MB
  const size_t needB = base2;

  if (ws_size >= needA){
    u16* Kt = w;
    u16* Vt = Kt + 8*KtB;
    u16* Ws = Vt + 8*VtB;
    float* Part = (float*)(Ws + 8*WsB);
    u16* Qs = w;                         // reuses Kt region after GEMM-A consumed it
    k_convert_kv<<<cgrid, blk, 0, stream>>>(K, V, Kt, Vt);
    // GEMM-A split-K: Part[z=kh*8+zb] = (Vt_zb . Kt_zb^T)|_khalf  (fp32 partials)
    k_gemm8<SEQ, 1, 4, 4><<<dim3(256), dim3(512), 0, stream>>>(
        Vt, Kt, Part, VtB, KtB, (size_t)1024*1024);
    k_reduce_split<<<dim3(8192), blk, 0, stream>>>(Part, Ws);
    k_split<<<dim3(2048), blk, 0, stream>>>(Q, Qs, 8*SEQ*(DIM/4));
    // GEMM-B: O = Qs . Ws^T  (fp32 out)
    k_gemm8<DIM, 0, 8, 4><<<dim3(256), dim3(512), 0, stream>>>(
        Qs, Ws, Out, QsB, WsB, (size_t)SEQ*DIM);
  } else if (ws_size >= needB){
    u16* Kt = w;
    u16* Vt = Kt + 8*KtB;
    u16* Ws = Vt + 8*VtB;
    u16* Qs = w;
    k_convert_kv<<<cgrid, blk, 0, stream>>>(K, V, Kt, Vt);
    k_gemm2ph<DIM, SEQ, 1, 8, 2, 4><<<dim3(512), blk, 0, stream>>>(Vt, Kt, Ws, VtB, KtB, WsB);
    k_split<<<dim3(2048), blk, 0, stream>>>(Q, Qs, 8*SEQ*(DIM/4));
    k_gemm8<DIM, 0, 8, 4><<<dim3(256), dim3(512), 0, stream>>>(
        Qs, Ws, Out, QsB, WsB, (size_t)SEQ*DIM);
  } else {
    // per-batch fallback
    u16* Qs = w;
    u16* Kt = Qs + QsB;
    u16* Vt = Kt + KtB;
    u16* Ws = Vt + VtB;
    for (int b = 0; b < BATCH; b++){
      const size_t inOff = (size_t)b * SEQ * DIM;
      k_split<<<dim3(1024), blk, 0, stream>>>(Q + inOff, Qs, SEQ*(DIM/4));
      k_convert_kv<<<dim3(SEQ/64, DIM/64, 1), blk, 0, stream>>>(K + inOff, K + inOff, Kt, Kt);
      k_convert_kv<<<dim3(SEQ/64, DIM/64, 1), blk, 0, stream>>>(V + inOff, V + inOff, Vt, Vt);
      k_gemm2ph<DIM, SEQ, 1, 8, 2, 4><<<dim3(64), blk, 0, stream>>>(Vt, Kt, Ws, VtB, KtB, WsB);
      k_gemm2ph<DIM, DIM, 0, 16, 4, 4><<<dim3(128), blk, 0, stream>>>(Qs, Ws, Out + inOff, QsB, WsB, (size_t)SEQ*DIM);
    }
  }
  k_softmax<<<dim3(BATCH*SEQ), blk, 0, stream>>>(Out);
}